// Round 14
// baseline (233.788 us; speedup 1.0000x reference)
//
#include <hip/hip_runtime.h>
#include <math.h>

#define D 128
#define ED 64
#define HD 32

typedef short s16x8 __attribute__((ext_vector_type(8)));
typedef unsigned short u16x8 __attribute__((ext_vector_type(8)));
typedef float f32x4 __attribute__((ext_vector_type(4)));

// f32 -> bf16 bits, round-to-nearest-even
static __device__ inline unsigned short f2b(float f) {
  unsigned int u = __float_as_uint(f);
  unsigned int r = (u + 0x7fff + ((u >> 16) & 1)) >> 16;
  return (unsigned short)r;
}
static __device__ inline float b2f(unsigned short b) {
  return __uint_as_float(((unsigned int)b) << 16);
}

// ---------- K1: count(rank) + weight preps + escore GEMV (all fused) ----------
__global__ __launch_bounds__(256)
void count_prep_kernel(const int* __restrict__ dst, int* __restrict__ cnt,
                       int* __restrict__ rank, int E, int egrid,
                       const float* __restrict__ g0W, unsigned short* __restrict__ Wt0,
                       const float* __restrict__ g1W, unsigned short* __restrict__ Wt1,
                       const float* __restrict__ ew0, unsigned short* __restrict__ ewt0,
                       const float* __restrict__ ew1, unsigned short* __restrict__ ewt1,
                       const float* __restrict__ g0We, const float* __restrict__ g0ae,
                       float* __restrict__ M0,
                       const float* __restrict__ g1We, const float* __restrict__ g1ae,
                       float* __restrict__ M1,
                       const float* __restrict__ x, const float* __restrict__ ow0,
                       const float* __restrict__ ob0, float* __restrict__ escore, int n) {
  int b = blockIdx.x, t = threadIdx.x;
  if (b < egrid) {
    int e = b * 256 + t;
    if (e < E) rank[e] = atomicAdd(&cnt[dst[e]], 1);   // rank within dst bucket
    return;
  }
  int pb = b - egrid;
  if (pb < 128) {                      // Wt[n][k] = bf16(W[k][n])
    const float* W = pb < 64 ? g0W : g1W;
    unsigned short* Wt = pb < 64 ? Wt0 : Wt1;
    int id = (pb & 63) * 256 + t;
    int nn = id >> 7, k = id & 127;
    Wt[id] = f2b(W[k * D + nn]);
  } else if (pb < 144) {               // permuted ewt
    const float* ew = pb < 136 ? ew0 : ew1;
    unsigned short* ewt = pb < 136 ? ewt0 : ewt1;
    int id = ((pb - 128) & 7) * 256 + t;
    if (id < HD * ED) {
      int i = id >> 6, k = id & 63;
      int ch = (i < 16) ? ((i >> 2) * 8 + (i & 3))
                        : (((i - 16) >> 2) * 8 + 4 + ((i - 16) & 3));
      ewt[id] = f2b(ew[k * HD + ch]);
    }
  } else if (pb == 144) {              // M0 [32][4]
    if (t < HD * 4) {
      int d = t >> 2, h = t & 3;
      float s = 0.f;
      for (int c = 0; c < 32; ++c) s += g0We[d * D + h * 32 + c] * g0ae[h * 32 + c];
      M0[t] = s;
    }
  } else if (pb == 145) {              // M1 [32]
    if (t < HD) {
      float s = 0.f;
      for (int c = 0; c < D; ++c) s += g1We[t * D + c] * g1ae[c];
      M1[t] = s;
    }
  } else {                             // escore GEMV: wave per node
    int node = (pb - 146) * 4 + (t >> 6);
    int lane = t & 63;
    if (node < n) {
      const float* xr = x + (size_t)node * D;
      float s = xr[lane] * ow0[lane] + xr[64 + lane] * ow0[64 + lane];
#pragma unroll
      for (int off = 32; off >= 1; off >>= 1) s += __shfl_xor(s, off);
      if (lane == 0) escore[node] = __expf(s + ob0[0]);
    }
  }
}

// ---------- hierarchical scan (coalesced, parallel) ----------
__global__ __launch_bounds__(256)
void scan_a_kernel(const int* __restrict__ cnt, int* __restrict__ bsum, int n) {
  __shared__ int sh[256];
  int t = threadIdx.x;
  int i = blockIdx.x * 256 + t;
  sh[t] = (i < n) ? cnt[i] : 0;
  __syncthreads();
  for (int off = 128; off >= 1; off >>= 1) {
    if (t < off) sh[t] += sh[t + off];
    __syncthreads();
  }
  if (t == 0) bsum[blockIdx.x] = sh[0];
}

__global__ __launch_bounds__(256)
void scan_b_kernel(const int* __restrict__ bsum, int* __restrict__ boff, int nb,
                   int* __restrict__ rowptr_n, int E) {
  __shared__ int sh[256];
  int t = threadIdx.x;
  int v = (t < nb) ? bsum[t] : 0;
  sh[t] = v;
  __syncthreads();
  for (int off = 1; off < 256; off <<= 1) {
    int add = (t >= off) ? sh[t - off] : 0;
    __syncthreads();
    sh[t] += add;
    __syncthreads();
  }
  if (t < nb) boff[t] = sh[t] - v;   // exclusive
  if (t == 0) *rowptr_n = E;
}

__global__ __launch_bounds__(256)
void scan_c_kernel(const int* __restrict__ cnt, const int* __restrict__ boff,
                   int* __restrict__ rowptr, int n) {
  __shared__ int sh[256];
  int t = threadIdx.x;
  int i = blockIdx.x * 256 + t;
  int v = (i < n) ? cnt[i] : 0;
  sh[t] = v;
  __syncthreads();
  for (int off = 1; off < 256; off <<= 1) {
    int add = (t >= off) ? sh[t - off] : 0;
    __syncthreads();
    sh[t] += add;
    __syncthreads();
  }
  if (i < n) rowptr[i] = boff[blockIdx.x] + sh[t] - v;  // exclusive prefix
}

// ---------- node GEMM + attention-logit epilogue (device body) ----------
template<int H, bool INBF16>
static __device__ void gemm_body(int gblk, int tid, const void* xin,
                                 const unsigned short* __restrict__ Wt,
                                 const float* __restrict__ a_s, const float* __restrict__ a_d,
                                 const float* __restrict__ ow, const float* __restrict__ ob,
                                 unsigned short* __restrict__ xs, float* __restrict__ al_src,
                                 float* __restrict__ al_dst,
                                 float2* __restrict__ als1, int n) {
  int wave = tid >> 6;
  int lane = tid & 63;
  int q = lane >> 4;
  int l16 = lane & 15;
  int base = gblk * 64 + wave * 16;
  int rowRaw = base + l16;
  int row = rowRaw < n ? rowRaw : n - 1;
  s16x8 a[4];
  float scp = 0.f;
  if (INBF16) {
    const unsigned short* xrow = (const unsigned short*)xin + (size_t)row * D;
#pragma unroll
    for (int kk = 0; kk < 4; ++kk) {
      int kb = kk * 32 + q * 8;
      u16x8 v = *(const u16x8*)(xrow + kb);
      if (H == 1) {
        float4 o0 = *(const float4*)(ow + kb);
        float4 o1 = *(const float4*)(ow + kb + 4);
        scp += b2f(v[0]) * o0.x + b2f(v[1]) * o0.y + b2f(v[2]) * o0.z + b2f(v[3]) * o0.w
             + b2f(v[4]) * o1.x + b2f(v[5]) * o1.y + b2f(v[6]) * o1.z + b2f(v[7]) * o1.w;
      }
      a[kk] = *(const s16x8*)&v;
    }
  } else {
    const float* xrow = (const float*)xin + (size_t)row * D;
#pragma unroll
    for (int kk = 0; kk < 4; ++kk) {
      int kb = kk * 32 + q * 8;
      float4 v0 = *(const float4*)(xrow + kb);
      float4 v1 = *(const float4*)(xrow + kb + 4);
      if (H == 1) {
        float4 o0 = *(const float4*)(ow + kb);
        float4 o1 = *(const float4*)(ow + kb + 4);
        scp += v0.x * o0.x + v0.y * o0.y + v0.z * o0.z + v0.w * o0.w
             + v1.x * o1.x + v1.y * o1.y + v1.z * o1.z + v1.w * o1.w;
      }
      s16x8 t;
      t[0] = (short)f2b(v0.x); t[1] = (short)f2b(v0.y);
      t[2] = (short)f2b(v0.z); t[3] = (short)f2b(v0.w);
      t[4] = (short)f2b(v1.x); t[5] = (short)f2b(v1.y);
      t[6] = (short)f2b(v1.z); t[7] = (short)f2b(v1.w);
      a[kk] = t;
    }
  }
  if (H == 1) {
    scp += __shfl_xor(scp, 16);
    scp += __shfl_xor(scp, 32);
  }

  f32x4 acc[8];
#pragma unroll
  for (int nf = 0; nf < 8; ++nf) { f32x4 z = {0.f, 0.f, 0.f, 0.f}; acc[nf] = z; }
#pragma unroll
  for (int kk = 0; kk < 4; ++kk) {
    int kb = kk * 32 + q * 8;
#pragma unroll
    for (int nf = 0; nf < 8; ++nf) {
      s16x8 b = *(const s16x8*)(Wt + (size_t)(nf * 16 + l16) * D + kb);
      acc[nf] = __builtin_amdgcn_mfma_f32_16x16x32_bf16(a[kk], b, acc[nf], 0, 0, 0);
    }
  }
#pragma unroll
  for (int nf = 0; nf < 8; ++nf) {
#pragma unroll
    for (int r = 0; r < 4; ++r) {
      int rr = base + q * 4 + r;
      if (rr < n) xs[(size_t)rr * D + nf * 16 + l16] = f2b(acc[nf][r]);
    }
  }
  float asv[8], adv[8];
#pragma unroll
  for (int nf = 0; nf < 8; ++nf) { asv[nf] = a_s[nf * 16 + l16]; adv[nf] = a_d[nf * 16 + l16]; }
  if (H == 4) {
    float mys = 0.f, myd = 0.f;
#pragma unroll
    for (int r = 0; r < 4; ++r) {
#pragma unroll
      for (int h = 0; h < 4; ++h) {
        float vs = acc[2 * h][r] * asv[2 * h] + acc[2 * h + 1][r] * asv[2 * h + 1];
        float vd = acc[2 * h][r] * adv[2 * h] + acc[2 * h + 1][r] * adv[2 * h + 1];
        vs += __shfl_xor(vs, 1); vd += __shfl_xor(vd, 1);
        vs += __shfl_xor(vs, 2); vd += __shfl_xor(vd, 2);
        vs += __shfl_xor(vs, 4); vd += __shfl_xor(vd, 4);
        vs += __shfl_xor(vs, 8); vd += __shfl_xor(vd, 8);
        if (l16 == r * 4 + h) { mys = vs; myd = vd; }
      }
    }
    int orow = base + q * 4 + (l16 >> 2);
    if (orow < n) {
      al_src[(size_t)orow * 4 + (l16 & 3)] = mys;
      al_dst[(size_t)orow * 4 + (l16 & 3)] = myd;
    }
  } else {
    float mys = 0.f, myd = 0.f;
#pragma unroll
    for (int r = 0; r < 4; ++r) {
      float vs = 0.f, vd = 0.f;
#pragma unroll
      for (int nf = 0; nf < 8; ++nf) { vs = fmaf(acc[nf][r], asv[nf], vs); vd = fmaf(acc[nf][r], adv[nf], vd); }
      vs += __shfl_xor(vs, 1); vd += __shfl_xor(vd, 1);
      vs += __shfl_xor(vs, 2); vd += __shfl_xor(vd, 2);
      vs += __shfl_xor(vs, 4); vd += __shfl_xor(vd, 4);
      vs += __shfl_xor(vs, 8); vd += __shfl_xor(vd, 8);
      if (l16 == r) { mys = vs; myd = vd; }
    }
    float scr = __shfl(scp, q * 4 + l16);
    int orow = base + q * 4 + l16;
    if (l16 < 4 && orow < n) {
      al_dst[orow] = myd;
      als1[orow] = make_float2(mys, __expf(scr + ob[0]));
    }
  }
}

// ---------- edge pass body: EDGE order, pure streaming + escore gather ----------
static __device__ void edge_body(int eblk, int tid,
                                 const int* __restrict__ src,
                                 const float* __restrict__ ea,
                                 const unsigned short* __restrict__ ewt0p,
                                 const unsigned short* __restrict__ ewt1p,
                                 const float* __restrict__ eb0, const float* __restrict__ eb1,
                                 const float* __restrict__ M0, const float* __restrict__ M1,
                                 const float* __restrict__ escore0,
                                 float* __restrict__ alef0,     // [E][4] edge order, escore-premult
                                 float* __restrict__ ale1raw,   // [E]   edge order, raw
                                 int E) {
  int wave = tid >> 6, lane = tid & 63;
  int q = lane >> 4, l16 = lane & 15;
  int ebase = (eblk * 4 + wave) * 64;
  if (ebase >= E) return;
  s16x8 a0l0 = *(const s16x8*)(ewt0p + l16 * 64 + q * 8);
  s16x8 a0l1 = *(const s16x8*)(ewt0p + l16 * 64 + 32 + q * 8);
  s16x8 a0h0 = *(const s16x8*)(ewt0p + (16 + l16) * 64 + q * 8);
  s16x8 a0h1 = *(const s16x8*)(ewt0p + (16 + l16) * 64 + 32 + q * 8);
  s16x8 a1l0 = *(const s16x8*)(ewt1p + l16 * 64 + q * 8);
  s16x8 a1l1 = *(const s16x8*)(ewt1p + l16 * 64 + 32 + q * 8);
  s16x8 a1h0 = *(const s16x8*)(ewt1p + (16 + l16) * 64 + q * 8);
  s16x8 a1h1 = *(const s16x8*)(ewt1p + (16 + l16) * 64 + 32 + q * 8);
  float4 b0lo = *(const float4*)(eb0 + q * 8);
  float4 b0hi = *(const float4*)(eb0 + q * 8 + 4);
  float4 b1lo = *(const float4*)(eb1 + q * 8);
  float4 b1hi = *(const float4*)(eb1 + q * 8 + 4);
  s16x8 mf0, mf1;
#pragma unroll
  for (int j = 0; j < 8; ++j) {
    mf0[j] = (l16 < 4) ? (short)f2b(M0[(q * 8 + j) * 4 + l16]) : (short)0;
    mf1[j] = (l16 == 0) ? (short)f2b(M1[q * 8 + j]) : (short)0;
  }
  int el = ebase + lane;
  int elc = el < E ? el : E - 1;
  float esc = escore0[src[elc]];          // my edge's source score (edge order)

#pragma unroll
  for (int st = 0; st < 4; ++st) {
    int slot16 = st * 16 + l16;
    int e16 = ebase + slot16;
    int ec = e16 < E ? e16 : E - 1;
    const float* er = ea + (size_t)ec * ED;   // streaming: sequential edge ids
    float4 u0 = *(const float4*)(er + q * 8);
    float4 u1 = *(const float4*)(er + q * 8 + 4);
    float4 u2 = *(const float4*)(er + 32 + q * 8);
    float4 u3 = *(const float4*)(er + 32 + q * 8 + 4);
    s16x8 bk0, bk1;
    bk0[0] = (short)f2b(u0.x); bk0[1] = (short)f2b(u0.y);
    bk0[2] = (short)f2b(u0.z); bk0[3] = (short)f2b(u0.w);
    bk0[4] = (short)f2b(u1.x); bk0[5] = (short)f2b(u1.y);
    bk0[6] = (short)f2b(u1.z); bk0[7] = (short)f2b(u1.w);
    bk1[0] = (short)f2b(u2.x); bk1[1] = (short)f2b(u2.y);
    bk1[2] = (short)f2b(u2.z); bk1[3] = (short)f2b(u2.w);
    bk1[4] = (short)f2b(u3.x); bk1[5] = (short)f2b(u3.y);
    bk1[6] = (short)f2b(u3.z); bk1[7] = (short)f2b(u3.w);
    f32x4 zl0 = {0.f,0.f,0.f,0.f}, zh0 = {0.f,0.f,0.f,0.f};
    f32x4 zl1 = {0.f,0.f,0.f,0.f}, zh1 = {0.f,0.f,0.f,0.f};
    zl0 = __builtin_amdgcn_mfma_f32_16x16x32_bf16(a0l0, bk0, zl0, 0, 0, 0);
    zl0 = __builtin_amdgcn_mfma_f32_16x16x32_bf16(a0l1, bk1, zl0, 0, 0, 0);
    zh0 = __builtin_amdgcn_mfma_f32_16x16x32_bf16(a0h0, bk0, zh0, 0, 0, 0);
    zh0 = __builtin_amdgcn_mfma_f32_16x16x32_bf16(a0h1, bk1, zh0, 0, 0, 0);
    zl1 = __builtin_amdgcn_mfma_f32_16x16x32_bf16(a1l0, bk0, zl1, 0, 0, 0);
    zl1 = __builtin_amdgcn_mfma_f32_16x16x32_bf16(a1l1, bk1, zl1, 0, 0, 0);
    zh1 = __builtin_amdgcn_mfma_f32_16x16x32_bf16(a1h0, bk0, zh1, 0, 0, 0);
    zh1 = __builtin_amdgcn_mfma_f32_16x16x32_bf16(a1h1, bk1, zh1, 0, 0, 0);
    s16x8 zb0, zb1;
    zb0[0] = (short)f2b(fmaxf(zl0[0] + b0lo.x, 0.f));
    zb0[1] = (short)f2b(fmaxf(zl0[1] + b0lo.y, 0.f));
    zb0[2] = (short)f2b(fmaxf(zl0[2] + b0lo.z, 0.f));
    zb0[3] = (short)f2b(fmaxf(zl0[3] + b0lo.w, 0.f));
    zb0[4] = (short)f2b(fmaxf(zh0[0] + b0hi.x, 0.f));
    zb0[5] = (short)f2b(fmaxf(zh0[1] + b0hi.y, 0.f));
    zb0[6] = (short)f2b(fmaxf(zh0[2] + b0hi.z, 0.f));
    zb0[7] = (short)f2b(fmaxf(zh0[3] + b0hi.w, 0.f));
    zb1[0] = (short)f2b(fmaxf(zl1[0] + b1lo.x, 0.f));
    zb1[1] = (short)f2b(fmaxf(zl1[1] + b1lo.y, 0.f));
    zb1[2] = (short)f2b(fmaxf(zl1[2] + b1lo.z, 0.f));
    zb1[3] = (short)f2b(fmaxf(zl1[3] + b1lo.w, 0.f));
    zb1[4] = (short)f2b(fmaxf(zh1[0] + b1hi.x, 0.f));
    zb1[5] = (short)f2b(fmaxf(zh1[1] + b1hi.y, 0.f));
    zb1[6] = (short)f2b(fmaxf(zh1[2] + b1hi.z, 0.f));
    zb1[7] = (short)f2b(fmaxf(zh1[3] + b1hi.w, 0.f));
    f32x4 r0 = {0.f,0.f,0.f,0.f}, r1 = {0.f,0.f,0.f,0.f};
    r0 = __builtin_amdgcn_mfma_f32_16x16x32_bf16(mf0, zb0, r0, 0, 0, 0);
    r1 = __builtin_amdgcn_mfma_f32_16x16x32_bf16(mf1, zb1, r1, 0, 0, 0);
    float esc_e = __shfl(esc, slot16);
    if (q == 0 && e16 < E) {
      *(float4*)(alef0 + (size_t)e16 * 4) =
          make_float4(r0[0] * esc_e, r0[1] * esc_e, r0[2] * esc_e, r0[3] * esc_e);
      ale1raw[e16] = r1[0];
    }
  }
}

// ---------- K3: fill + gemm0 + edge pass (fused, three independent block ranges) ----------
__global__ __launch_bounds__(256)
void mega_kernel(const int* __restrict__ src, const int* __restrict__ dst,
                 const int* __restrict__ rowptr, const int* __restrict__ rank,
                 int2* __restrict__ slotmap, int E, int fgrid, int ggrid,
                 const float* __restrict__ x, const unsigned short* __restrict__ Wt0,
                 const float* __restrict__ g0as, const float* __restrict__ g0ad,
                 unsigned short* __restrict__ xs, float* __restrict__ al_src,
                 float* __restrict__ al_dst, int n,
                 const float* __restrict__ ea,
                 const unsigned short* __restrict__ ewt0p,
                 const unsigned short* __restrict__ ewt1p,
                 const float* __restrict__ eb0, const float* __restrict__ eb1,
                 const float* __restrict__ M0, const float* __restrict__ M1,
                 const float* __restrict__ escore,
                 float* __restrict__ alef0, float* __restrict__ ale1raw) {
  int b = blockIdx.x;
  if (b < fgrid) {
    int e = b * 256 + threadIdx.x;
    if (e < E) {
      int d = dst[e];
      slotmap[rowptr[d] + rank[e]] = make_int2(e, src[e]);   // no atomics
    }
  } else if (b < fgrid + ggrid) {
    gemm_body<4, false>(b - fgrid, threadIdx.x, x, Wt0, g0as, g0ad, nullptr, nullptr,
                        xs, al_src, al_dst, nullptr, n);
  } else {
    edge_body(b - fgrid - ggrid, threadIdx.x, src, ea, ewt0p, ewt1p,
              eb0, eb1, M0, M1, escore, alef0, ale1raw, E);
  }
}

__global__ __launch_bounds__(256)
void gemm1_kernel(const unsigned short* __restrict__ x1b, const unsigned short* __restrict__ Wt,
                  const float* __restrict__ a_s, const float* __restrict__ a_d,
                  const float* __restrict__ ow, const float* __restrict__ ob,
                  unsigned short* __restrict__ xs, float* __restrict__ al_dst,
                  float2* __restrict__ als1, int n) {
  gemm_body<1, true>(blockIdx.x, threadIdx.x, x1b, Wt, a_s, a_d, ow, ob,
                     xs, nullptr, al_dst, als1, n);
}

// ---------- CSR aggregation: half-wave per edge, predicated rounds (round-11 form) ----------
template<int H, bool RELU, bool ADD_ORIG, bool INBF16, bool OUTBF16>
__global__ __launch_bounds__(256)
void agg_kernel(const int* __restrict__ rowptr, const int2* __restrict__ slotmap,
                const unsigned short* __restrict__ xs, const float* __restrict__ alef,
                const float* __restrict__ al_src, const float* __restrict__ al_dst,
                const float2* __restrict__ als1,
                const float* __restrict__ bias, const void* __restrict__ xin,
                const float* __restrict__ orig, void* __restrict__ outv, int n) {
  int wid = blockIdx.x * 4 + (threadIdx.x >> 6);
  int lane = threadIdx.x & 63;
  if (wid >= n) return;
  int half = lane >> 5;
  int l32 = lane & 31;
  int h0 = (H == 4) ? (l32 >> 3) : 0;   // lane covers channels 4*l32..4*l32+3
  const ushort4* xs4 = (const ushort4*)xs;
  float adst = al_dst[(size_t)wid * H + h0];
  float ax0 = 0.f, ax1 = 0.f, ax2 = 0.f, ax3 = 0.f, den = 0.f, sale = 0.f;
  int b = rowptr[wid], e = rowptr[wid + 1];
  int m = e - b;

#define EDGE_ACC(I_)                                                     \
  {                                                                      \
    int idx_ = (I_);                                                     \
    bool v_ = idx_ < e;                                                  \
    int ic_ = v_ ? idx_ : b;                                             \
    int2 sm_ = slotmap[ic_];                                             \
    int s_ = sm_.y;                                                      \
    int eo_ = sm_.x;                                                     \
    float al_, ev_;                                                      \
    if (H == 4) {                                                        \
      al_ = alef[(size_t)eo_ * 4 + h0];                                  \
      float aa_ = al_src[(size_t)s_ * 4 + h0] + adst + al_;              \
      ev_ = __expf(aa_ > 0.f ? aa_ : 0.2f * aa_);                        \
    } else {                                                             \
      float2 ae_ = als1[s_];                                             \
      al_ = alef[eo_] * ae_.y;                                           \
      float aa_ = ae_.x + adst + al_;                                    \
      ev_ = __expf(aa_ > 0.f ? aa_ : 0.2f * aa_);                        \
    }                                                                    \
    if (!v_) { ev_ = 0.f; al_ = 0.f; }                                   \
    ushort4 u_ = xs4[(size_t)s_ * 32 + l32];                             \
    ax0 = fmaf(ev_, b2f(u_.x), ax0); ax1 = fmaf(ev_, b2f(u_.y), ax1);    \
    ax2 = fmaf(ev_, b2f(u_.z), ax2); ax3 = fmaf(ev_, b2f(u_.w), ax3);    \
    den += ev_; sale += al_;                                             \
  }

  for (int k = 0; k < m; k += 8) {
    int i0 = b + k + half;
    EDGE_ACC(i0)
    EDGE_ACC(i0 + 2)
    EDGE_ACC(i0 + 4)
    EDGE_ACC(i0 + 6)
  }
#undef EDGE_ACC

  // cross-half combine (partner lane has same l32/h0)
  ax0 += __shfl_xor(ax0, 32); ax1 += __shfl_xor(ax1, 32);
  ax2 += __shfl_xor(ax2, 32); ax3 += __shfl_xor(ax3, 32);
  den += __shfl_xor(den, 32); sale += __shfl_xor(sale, 32);

  // self-loop: attr = mean of incoming alef (linear in attr)
  float la = sale / (float)(m > 1 ? m : 1);
  float asrc_w = (H == 4) ? al_src[(size_t)wid * 4 + h0] : als1[wid].x;
  float a = asrc_w + adst + la;
  float lr = a > 0.f ? a : 0.2f * a;
  float evl = __expf(lr);
  ushort4 us = xs4[(size_t)wid * 32 + l32];
  ax0 = fmaf(evl, b2f(us.x), ax0); ax1 = fmaf(evl, b2f(us.y), ax1);
  ax2 = fmaf(evl, b2f(us.z), ax2); ax3 = fmaf(evl, b2f(us.w), ax3);
  float dinv = 1.f / (den + evl + 1e-16f);
  if (half == 0) {
    float4 bi = ((const float4*)bias)[l32];
    float o0 = ax0 * dinv + bi.x;
    float o1 = ax1 * dinv + bi.y;
    float o2 = ax2 * dinv + bi.z;
    float o3 = ax3 * dinv + bi.w;
    if (INBF16) {
      ushort4 xi = ((const ushort4*)xin)[(size_t)wid * 32 + l32];
      o0 += b2f(xi.x); o1 += b2f(xi.y); o2 += b2f(xi.z); o3 += b2f(xi.w);
    } else {
      float4 xi = ((const float4*)xin)[(size_t)wid * 32 + l32];
      o0 += xi.x; o1 += xi.y; o2 += xi.z; o3 += xi.w;
    }
    if (ADD_ORIG) {
      float4 og = ((const float4*)orig)[(size_t)wid * 32 + l32];
      o0 += og.x; o1 += og.y; o2 += og.z; o3 += og.w;
    }
    if (RELU) {
      o0 = fmaxf(o0, 0.f); o1 = fmaxf(o1, 0.f);
      o2 = fmaxf(o2, 0.f); o3 = fmaxf(o3, 0.f);
    }
    if (OUTBF16) {
      ushort4 ob;
      ob.x = f2b(o0); ob.y = f2b(o1); ob.z = f2b(o2); ob.w = f2b(o3);
      ((ushort4*)outv)[(size_t)wid * 32 + l32] = ob;
    } else {
      ((float4*)outv)[(size_t)wid * 32 + l32] = make_float4(o0, o1, o2, o3);
    }
  }
}

extern "C" void kernel_launch(void* const* d_in, const int* in_sizes, int n_in,
                              void* d_out, int out_size, void* d_ws, size_t ws_size,
                              hipStream_t stream) {
  const float* x   = (const float*)d_in[0];
  const int*   ei  = (const int*)d_in[1];
  const float* ea  = (const float*)d_in[2];
  const float* ew0 = (const float*)d_in[3];
  const float* eb0 = (const float*)d_in[4];
  const float* ew1 = (const float*)d_in[5];
  const float* eb1 = (const float*)d_in[6];
  const float* ow0 = (const float*)d_in[7];
  const float* ob0 = (const float*)d_in[8];
  const float* ow1 = (const float*)d_in[9];
  const float* ob1 = (const float*)d_in[10];
  const float* g0W = (const float*)d_in[11];
  const float* g0as= (const float*)d_in[12];
  const float* g0ad= (const float*)d_in[13];
  const float* g0We= (const float*)d_in[14];
  const float* g0ae= (const float*)d_in[15];
  const float* g0b = (const float*)d_in[16];
  const float* g1W = (const float*)d_in[17];
  const float* g1as= (const float*)d_in[18];
  const float* g1ad= (const float*)d_in[19];
  const float* g1We= (const float*)d_in[20];
  const float* g1ae= (const float*)d_in[21];
  const float* g1b = (const float*)d_in[22];
  float* out = (float*)d_out;

  const int N = in_sizes[0] / D;
  const int E = in_sizes[1] / 2;
  const int* srcp = ei;
  const int* dstp = ei + E;

  char* w = (char*)d_ws;
  size_t off = 0;
  auto alloc = [&](size_t bytes) {
    void* p = w + off;
    off += (bytes + 255) & ~(size_t)255;
    return p;
  };
  size_t Nb = ((size_t)N * 4 + 255) & ~(size_t)255;
  int*   cnt     = (int*)alloc(Nb);
  int*   rank    = (int*)alloc((size_t)E * 4);
  unsigned short* xs   = (unsigned short*)alloc((size_t)N * D * 2);
  unsigned short* x1b  = (unsigned short*)alloc((size_t)N * D * 2);
  float* alef0   = (float*)alloc((size_t)E * 4 * 4);
  float* ale1raw = (float*)alloc((size_t)E * 4);
  float* al_src  = (float*)alloc((size_t)N * 4 * 4);
  float* al_dst  = (float*)alloc((size_t)N * 4 * 4);
  float* escore  = (float*)alloc((size_t)N * 4);
  float2* als1   = (float2*)alloc((size_t)N * 8);
  float* M0      = (float*)alloc(HD * 4 * 4);
  float* M1      = (float*)alloc(HD * 4);
  unsigned short* Wt0 = (unsigned short*)alloc((size_t)D * D * 2);
  unsigned short* Wt1 = (unsigned short*)alloc((size_t)D * D * 2);
  unsigned short* ewt0 = (unsigned short*)alloc((size_t)HD * ED * 2);
  unsigned short* ewt1 = (unsigned short*)alloc((size_t)HD * ED * 2);
  int*   rowptr  = (int*)alloc((size_t)(N + 1) * 4);
  int2*  slotmap = (int2*)alloc((size_t)E * 8);
  int*   bsum    = (int*)alloc(1024);
  int*   boff    = (int*)alloc(1024);

  int egrid  = (E + 255) / 256;
  int ngrid4 = (N + 3) / 4;
  int ggrid  = (N + 63) / 64;
  int nsb    = (N + 255) / 256;

  hipMemsetAsync(cnt, 0, Nb, stream);
  count_prep_kernel<<<egrid + 146 + ngrid4, 256, 0, stream>>>(
      dstp, cnt, rank, E, egrid,
      g0W, Wt0, g1W, Wt1, ew0, ewt0, ew1, ewt1,
      g0We, g0ae, M0, g1We, g1ae, M1,
      x, ow0, ob0, escore, N);
  scan_a_kernel<<<nsb, 256, 0, stream>>>(cnt, bsum, N);
  scan_b_kernel<<<1, 256, 0, stream>>>(bsum, boff, nsb, rowptr + N, E);
  scan_c_kernel<<<nsb, 256, 0, stream>>>(cnt, boff, rowptr, N);
  mega_kernel<<<egrid + ggrid + egrid, 256, 0, stream>>>(
      srcp, dstp, rowptr, rank, slotmap, E, egrid, ggrid,
      x, Wt0, g0as, g0ad, xs, al_src, al_dst, N,
      ea, ewt0, ewt1, eb0, eb1, M0, M1, escore, alef0, ale1raw);
  // layer-0 aggregation -> x1 (bf16 in workspace)
  agg_kernel<4, true, false, false, true><<<ngrid4, 256, 0, stream>>>(
      rowptr, slotmap, xs, alef0, al_src, al_dst, nullptr,
      g0b, x, nullptr, x1b, N);
  gemm1_kernel<<<ggrid, 256, 0, stream>>>(x1b, Wt1, g1as, g1ad, ow1, ob1,
                                          xs, al_dst, als1, N);
  // layer-1 aggregation -> final f32 out (residual x1b + original x)
  agg_kernel<1, false, true, true, false><<<ngrid4, 256, 0, stream>>>(
      rowptr, slotmap, xs, ale1raw, nullptr, al_dst, als1,
      g1b, x1b, x, out, N);
}

// Round 15
// 220.766 us; speedup vs baseline: 1.0590x; 1.0590x over previous
//
#include <hip/hip_runtime.h>
#include <math.h>

#define D 128
#define ED 64
#define HD 32

typedef short s16x8 __attribute__((ext_vector_type(8)));
typedef unsigned short u16x8 __attribute__((ext_vector_type(8)));
typedef float f32x4 __attribute__((ext_vector_type(4)));

// f32 -> bf16 bits, round-to-nearest-even
static __device__ inline unsigned short f2b(float f) {
  unsigned int u = __float_as_uint(f);
  unsigned int r = (u + 0x7fff + ((u >> 16) & 1)) >> 16;
  return (unsigned short)r;
}
static __device__ inline float b2f(unsigned short b) {
  return __uint_as_float(((unsigned int)b) << 16);
}

// ---------- K1: count (stores bucket rank) + all weight preps (fused) ----------
__global__ __launch_bounds__(256)
void count_prep_kernel(const int* __restrict__ dst, int* __restrict__ cnt,
                       int* __restrict__ rank, int E, int egrid,
                       const float* __restrict__ g0W, unsigned short* __restrict__ Wt0,
                       const float* __restrict__ g1W, unsigned short* __restrict__ Wt1,
                       const float* __restrict__ ew0, unsigned short* __restrict__ ewt0,
                       const float* __restrict__ ew1, unsigned short* __restrict__ ewt1,
                       const float* __restrict__ g0We, const float* __restrict__ g0ae,
                       float* __restrict__ M0,
                       const float* __restrict__ g1We, const float* __restrict__ g1ae,
                       float* __restrict__ M1) {
  int b = blockIdx.x, t = threadIdx.x;
  if (b < egrid) {
    int e = b * 256 + t;
    if (e < E) rank[e] = atomicAdd(&cnt[dst[e]], 1);   // rank within dst bucket
    return;
  }
  int pb = b - egrid;
  if (pb < 128) {                      // Wt[n][k] = bf16(W[k][n])
    const float* W = pb < 64 ? g0W : g1W;
    unsigned short* Wt = pb < 64 ? Wt0 : Wt1;
    int id = (pb & 63) * 256 + t;
    int nn = id >> 7, k = id & 127;
    Wt[id] = f2b(W[k * D + nn]);
  } else if (pb < 144) {               // permuted ewt
    const float* ew = pb < 136 ? ew0 : ew1;
    unsigned short* ewt = pb < 136 ? ewt0 : ewt1;
    int id = ((pb - 128) & 7) * 256 + t;
    if (id < HD * ED) {
      int i = id >> 6, k = id & 63;
      int ch = (i < 16) ? ((i >> 2) * 8 + (i & 3))
                        : (((i - 16) >> 2) * 8 + 4 + ((i - 16) & 3));
      ewt[id] = f2b(ew[k * HD + ch]);
    }
  } else if (pb == 144) {              // M0 [32][4]
    if (t < HD * 4) {
      int d = t >> 2, h = t & 3;
      float s = 0.f;
      for (int c = 0; c < 32; ++c) s += g0We[d * D + h * 32 + c] * g0ae[h * 32 + c];
      M0[t] = s;
    }
  } else {                             // M1 [32]
    if (t < HD) {
      float s = 0.f;
      for (int c = 0; c < D; ++c) s += g1We[t * D + c] * g1ae[c];
      M1[t] = s;
    }
  }
}

// ---------- hierarchical scan (coalesced, parallel) ----------
__global__ __launch_bounds__(256)
void scan_a_kernel(const int* __restrict__ cnt, int* __restrict__ bsum, int n) {
  __shared__ int sh[256];
  int t = threadIdx.x;
  int i = blockIdx.x * 256 + t;
  sh[t] = (i < n) ? cnt[i] : 0;
  __syncthreads();
  for (int off = 128; off >= 1; off >>= 1) {
    if (t < off) sh[t] += sh[t + off];
    __syncthreads();
  }
  if (t == 0) bsum[blockIdx.x] = sh[0];
}

__global__ __launch_bounds__(256)
void scan_b_kernel(const int* __restrict__ bsum, int* __restrict__ boff, int nb,
                   int* __restrict__ rowptr_n, int E) {
  __shared__ int sh[256];
  int t = threadIdx.x;
  int v = (t < nb) ? bsum[t] : 0;
  sh[t] = v;
  __syncthreads();
  for (int off = 1; off < 256; off <<= 1) {
    int add = (t >= off) ? sh[t - off] : 0;
    __syncthreads();
    sh[t] += add;
    __syncthreads();
  }
  if (t < nb) boff[t] = sh[t] - v;   // exclusive
  if (t == 0) *rowptr_n = E;
}

__global__ __launch_bounds__(256)
void scan_c_kernel(const int* __restrict__ cnt, const int* __restrict__ boff,
                   int* __restrict__ rowptr, int n) {
  __shared__ int sh[256];
  int t = threadIdx.x;
  int i = blockIdx.x * 256 + t;
  int v = (i < n) ? cnt[i] : 0;
  sh[t] = v;
  __syncthreads();
  for (int off = 1; off < 256; off <<= 1) {
    int add = (t >= off) ? sh[t - off] : 0;
    __syncthreads();
    sh[t] += add;
    __syncthreads();
  }
  if (i < n) rowptr[i] = boff[blockIdx.x] + sh[t] - v;  // exclusive prefix
}

// ---------- node GEMM + attention-logit epilogue (device body) ----------
template<int H, bool INBF16>
static __device__ void gemm_body(int gblk, int tid, const void* xin,
                                 const unsigned short* __restrict__ Wt,
                                 const float* __restrict__ a_s, const float* __restrict__ a_d,
                                 const float* __restrict__ ow, const float* __restrict__ ob,
                                 unsigned short* __restrict__ xs, float* __restrict__ al_src,
                                 float* __restrict__ al_dst, float* __restrict__ escore,
                                 float2* __restrict__ als1, int n) {
  int wave = tid >> 6;
  int lane = tid & 63;
  int q = lane >> 4;
  int l16 = lane & 15;
  int base = gblk * 64 + wave * 16;
  int rowRaw = base + l16;
  int row = rowRaw < n ? rowRaw : n - 1;
  s16x8 a[4];
  float scp = 0.f;
  if (INBF16) {
    const unsigned short* xrow = (const unsigned short*)xin + (size_t)row * D;
#pragma unroll
    for (int kk = 0; kk < 4; ++kk) {
      int kb = kk * 32 + q * 8;
      u16x8 v = *(const u16x8*)(xrow + kb);
      float4 o0 = *(const float4*)(ow + kb);
      float4 o1 = *(const float4*)(ow + kb + 4);
      scp += b2f(v[0]) * o0.x + b2f(v[1]) * o0.y + b2f(v[2]) * o0.z + b2f(v[3]) * o0.w
           + b2f(v[4]) * o1.x + b2f(v[5]) * o1.y + b2f(v[6]) * o1.z + b2f(v[7]) * o1.w;
      a[kk] = *(const s16x8*)&v;
    }
  } else {
    const float* xrow = (const float*)xin + (size_t)row * D;
#pragma unroll
    for (int kk = 0; kk < 4; ++kk) {
      int kb = kk * 32 + q * 8;
      float4 v0 = *(const float4*)(xrow + kb);
      float4 v1 = *(const float4*)(xrow + kb + 4);
      float4 o0 = *(const float4*)(ow + kb);
      float4 o1 = *(const float4*)(ow + kb + 4);
      scp += v0.x * o0.x + v0.y * o0.y + v0.z * o0.z + v0.w * o0.w
           + v1.x * o1.x + v1.y * o1.y + v1.z * o1.z + v1.w * o1.w;
      s16x8 t;
      t[0] = (short)f2b(v0.x); t[1] = (short)f2b(v0.y);
      t[2] = (short)f2b(v0.z); t[3] = (short)f2b(v0.w);
      t[4] = (short)f2b(v1.x); t[5] = (short)f2b(v1.y);
      t[6] = (short)f2b(v1.z); t[7] = (short)f2b(v1.w);
      a[kk] = t;
    }
  }
  scp += __shfl_xor(scp, 16);
  scp += __shfl_xor(scp, 32);
  if (H == 4) {
    if (q == 0 && rowRaw < n) escore[rowRaw] = __expf(scp + ob[0]);
  }

  f32x4 acc[8];
#pragma unroll
  for (int nf = 0; nf < 8; ++nf) { f32x4 z = {0.f, 0.f, 0.f, 0.f}; acc[nf] = z; }
#pragma unroll
  for (int kk = 0; kk < 4; ++kk) {
    int kb = kk * 32 + q * 8;
#pragma unroll
    for (int nf = 0; nf < 8; ++nf) {
      s16x8 b = *(const s16x8*)(Wt + (size_t)(nf * 16 + l16) * D + kb);
      acc[nf] = __builtin_amdgcn_mfma_f32_16x16x32_bf16(a[kk], b, acc[nf], 0, 0, 0);
    }
  }
#pragma unroll
  for (int nf = 0; nf < 8; ++nf) {
#pragma unroll
    for (int r = 0; r < 4; ++r) {
      int rr = base + q * 4 + r;
      if (rr < n) xs[(size_t)rr * D + nf * 16 + l16] = f2b(acc[nf][r]);
    }
  }
  float asv[8], adv[8];
#pragma unroll
  for (int nf = 0; nf < 8; ++nf) { asv[nf] = a_s[nf * 16 + l16]; adv[nf] = a_d[nf * 16 + l16]; }
  if (H == 4) {
    float mys = 0.f, myd = 0.f;
#pragma unroll
    for (int r = 0; r < 4; ++r) {
#pragma unroll
      for (int h = 0; h < 4; ++h) {
        float vs = acc[2 * h][r] * asv[2 * h] + acc[2 * h + 1][r] * asv[2 * h + 1];
        float vd = acc[2 * h][r] * adv[2 * h] + acc[2 * h + 1][r] * adv[2 * h + 1];
        vs += __shfl_xor(vs, 1); vd += __shfl_xor(vd, 1);
        vs += __shfl_xor(vs, 2); vd += __shfl_xor(vd, 2);
        vs += __shfl_xor(vs, 4); vd += __shfl_xor(vd, 4);
        vs += __shfl_xor(vs, 8); vd += __shfl_xor(vd, 8);
        if (l16 == r * 4 + h) { mys = vs; myd = vd; }
      }
    }
    int orow = base + q * 4 + (l16 >> 2);
    if (orow < n) {
      al_src[(size_t)orow * 4 + (l16 & 3)] = mys;
      al_dst[(size_t)orow * 4 + (l16 & 3)] = myd;
    }
  } else {
    float mys = 0.f, myd = 0.f;
#pragma unroll
    for (int r = 0; r < 4; ++r) {
      float vs = 0.f, vd = 0.f;
#pragma unroll
      for (int nf = 0; nf < 8; ++nf) { vs = fmaf(acc[nf][r], asv[nf], vs); vd = fmaf(acc[nf][r], adv[nf], vd); }
      vs += __shfl_xor(vs, 1); vd += __shfl_xor(vd, 1);
      vs += __shfl_xor(vs, 2); vd += __shfl_xor(vd, 2);
      vs += __shfl_xor(vs, 4); vd += __shfl_xor(vd, 4);
      vs += __shfl_xor(vs, 8); vd += __shfl_xor(vd, 8);
      if (l16 == r) { mys = vs; myd = vd; }
    }
    float scr = __shfl(scp, q * 4 + l16);
    int orow = base + q * 4 + l16;
    if (l16 < 4 && orow < n) {
      al_dst[orow] = myd;
      als1[orow] = make_float2(mys, __expf(scr + ob[0]));
    }
  }
}

// ---------- K3: fill (atomic-free scatter) + gemm0 (fused, independent halves) ----------
__global__ __launch_bounds__(256)
void fill_gemm_kernel(const int* __restrict__ src, const int* __restrict__ dst,
                      const int* __restrict__ rowptr, const int* __restrict__ rank,
                      int2* __restrict__ slotmap, int E, int fgrid,
                      const float* __restrict__ x, const unsigned short* __restrict__ Wt0,
                      const float* __restrict__ g0as, const float* __restrict__ g0ad,
                      const float* __restrict__ ow0, const float* __restrict__ ob0,
                      unsigned short* __restrict__ xs, float* __restrict__ al_src,
                      float* __restrict__ al_dst, float* __restrict__ escore, int n) {
  if ((int)blockIdx.x < fgrid) {
    int e = blockIdx.x * 256 + threadIdx.x;
    if (e < E) {
      int d = dst[e];
      slotmap[rowptr[d] + rank[e]] = make_int2(e, src[e]);   // no atomics
    }
  } else {
    gemm_body<4, false>(blockIdx.x - fgrid, threadIdx.x, x, Wt0, g0as, g0ad, ow0, ob0,
                        xs, al_src, al_dst, escore, nullptr, n);
  }
}

__global__ __launch_bounds__(256)
void gemm1_kernel(const unsigned short* __restrict__ x1b, const unsigned short* __restrict__ Wt,
                  const float* __restrict__ a_s, const float* __restrict__ a_d,
                  const float* __restrict__ ow, const float* __restrict__ ob,
                  unsigned short* __restrict__ xs, float* __restrict__ al_dst,
                  float2* __restrict__ als1, int n) {
  gemm_body<1, true>(blockIdx.x, threadIdx.x, x1b, Wt, a_s, a_d, ow, ob,
                     xs, nullptr, al_dst, nullptr, als1, n);
}

// ---------- K4: edge pass in CSR order (gathers ea rows, streams outputs) ----------
__global__ __launch_bounds__(256)
void edge_csr_kernel(const int2* __restrict__ slotmap,
                     const float* __restrict__ ea,
                     const unsigned short* __restrict__ ewt0p,
                     const unsigned short* __restrict__ ewt1p,
                     const float* __restrict__ eb0, const float* __restrict__ eb1,
                     const float* __restrict__ M0, const float* __restrict__ M1,
                     const float* __restrict__ escore0,
                     float* __restrict__ alef0,     // [E][4] CSR order, escore-premultiplied
                     float* __restrict__ ale1raw,   // [E]   CSR order, raw
                     int E) {
  int wave = threadIdx.x >> 6, lane = threadIdx.x & 63;
  int q = lane >> 4, l16 = lane & 15;
  int ebase = (blockIdx.x * 4 + wave) * 64;
  if (ebase >= E) return;
  s16x8 a0l0 = *(const s16x8*)(ewt0p + l16 * 64 + q * 8);
  s16x8 a0l1 = *(const s16x8*)(ewt0p + l16 * 64 + 32 + q * 8);
  s16x8 a0h0 = *(const s16x8*)(ewt0p + (16 + l16) * 64 + q * 8);
  s16x8 a0h1 = *(const s16x8*)(ewt0p + (16 + l16) * 64 + 32 + q * 8);
  s16x8 a1l0 = *(const s16x8*)(ewt1p + l16 * 64 + q * 8);
  s16x8 a1l1 = *(const s16x8*)(ewt1p + l16 * 64 + 32 + q * 8);
  s16x8 a1h0 = *(const s16x8*)(ewt1p + (16 + l16) * 64 + q * 8);
  s16x8 a1h1 = *(const s16x8*)(ewt1p + (16 + l16) * 64 + 32 + q * 8);
  float4 b0lo = *(const float4*)(eb0 + q * 8);
  float4 b0hi = *(const float4*)(eb0 + q * 8 + 4);
  float4 b1lo = *(const float4*)(eb1 + q * 8);
  float4 b1hi = *(const float4*)(eb1 + q * 8 + 4);
  s16x8 mf0, mf1;
#pragma unroll
  for (int j = 0; j < 8; ++j) {
    mf0[j] = (l16 < 4) ? (short)f2b(M0[(q * 8 + j) * 4 + l16]) : (short)0;
    mf1[j] = (l16 == 0) ? (short)f2b(M1[q * 8 + j]) : (short)0;
  }
  int el = ebase + lane;
  int elc = el < E ? el : E - 1;
  int2 sm = slotmap[elc];
  int eo = sm.x;                           // original edge id for my CSR slot
  float esc = escore0[sm.y];               // escore of my slot's src

#pragma unroll
  for (int st = 0; st < 4; ++st) {
    int slot16 = st * 16 + l16;
    int e16 = ebase + slot16;
    int row = __shfl(eo, slot16);
    const float* er = ea + (size_t)row * ED;
    float4 u0 = *(const float4*)(er + q * 8);
    float4 u1 = *(const float4*)(er + q * 8 + 4);
    float4 u2 = *(const float4*)(er + 32 + q * 8);
    float4 u3 = *(const float4*)(er + 32 + q * 8 + 4);
    s16x8 bk0, bk1;
    bk0[0] = (short)f2b(u0.x); bk0[1] = (short)f2b(u0.y);
    bk0[2] = (short)f2b(u0.z); bk0[3] = (short)f2b(u0.w);
    bk0[4] = (short)f2b(u1.x); bk0[5] = (short)f2b(u1.y);
    bk0[6] = (short)f2b(u1.z); bk0[7] = (short)f2b(u1.w);
    bk1[0] = (short)f2b(u2.x); bk1[1] = (short)f2b(u2.y);
    bk1[2] = (short)f2b(u2.z); bk1[3] = (short)f2b(u2.w);
    bk1[4] = (short)f2b(u3.x); bk1[5] = (short)f2b(u3.y);
    bk1[6] = (short)f2b(u3.z); bk1[7] = (short)f2b(u3.w);
    f32x4 zl0 = {0.f,0.f,0.f,0.f}, zh0 = {0.f,0.f,0.f,0.f};
    f32x4 zl1 = {0.f,0.f,0.f,0.f}, zh1 = {0.f,0.f,0.f,0.f};
    zl0 = __builtin_amdgcn_mfma_f32_16x16x32_bf16(a0l0, bk0, zl0, 0, 0, 0);
    zl0 = __builtin_amdgcn_mfma_f32_16x16x32_bf16(a0l1, bk1, zl0, 0, 0, 0);
    zh0 = __builtin_amdgcn_mfma_f32_16x16x32_bf16(a0h0, bk0, zh0, 0, 0, 0);
    zh0 = __builtin_amdgcn_mfma_f32_16x16x32_bf16(a0h1, bk1, zh0, 0, 0, 0);
    zl1 = __builtin_amdgcn_mfma_f32_16x16x32_bf16(a1l0, bk0, zl1, 0, 0, 0);
    zl1 = __builtin_amdgcn_mfma_f32_16x16x32_bf16(a1l1, bk1, zl1, 0, 0, 0);
    zh1 = __builtin_amdgcn_mfma_f32_16x16x32_bf16(a1h0, bk0, zh1, 0, 0, 0);
    zh1 = __builtin_amdgcn_mfma_f32_16x16x32_bf16(a1h1, bk1, zh1, 0, 0, 0);
    s16x8 zb0, zb1;
    zb0[0] = (short)f2b(fmaxf(zl0[0] + b0lo.x, 0.f));
    zb0[1] = (short)f2b(fmaxf(zl0[1] + b0lo.y, 0.f));
    zb0[2] = (short)f2b(fmaxf(zl0[2] + b0lo.z, 0.f));
    zb0[3] = (short)f2b(fmaxf(zl0[3] + b0lo.w, 0.f));
    zb0[4] = (short)f2b(fmaxf(zh0[0] + b0hi.x, 0.f));
    zb0[5] = (short)f2b(fmaxf(zh0[1] + b0hi.y, 0.f));
    zb0[6] = (short)f2b(fmaxf(zh0[2] + b0hi.z, 0.f));
    zb0[7] = (short)f2b(fmaxf(zh0[3] + b0hi.w, 0.f));
    zb1[0] = (short)f2b(fmaxf(zl1[0] + b1lo.x, 0.f));
    zb1[1] = (short)f2b(fmaxf(zl1[1] + b1lo.y, 0.f));
    zb1[2] = (short)f2b(fmaxf(zl1[2] + b1lo.z, 0.f));
    zb1[3] = (short)f2b(fmaxf(zl1[3] + b1lo.w, 0.f));
    zb1[4] = (short)f2b(fmaxf(zh1[0] + b1hi.x, 0.f));
    zb1[5] = (short)f2b(fmaxf(zh1[1] + b1hi.y, 0.f));
    zb1[6] = (short)f2b(fmaxf(zh1[2] + b1hi.z, 0.f));
    zb1[7] = (short)f2b(fmaxf(zh1[3] + b1hi.w, 0.f));
    f32x4 r0 = {0.f,0.f,0.f,0.f}, r1 = {0.f,0.f,0.f,0.f};
    r0 = __builtin_amdgcn_mfma_f32_16x16x32_bf16(mf0, zb0, r0, 0, 0, 0);
    r1 = __builtin_amdgcn_mfma_f32_16x16x32_bf16(mf1, zb1, r1, 0, 0, 0);
    float esc_e = __shfl(esc, slot16);
    if (q == 0 && e16 < E) {
      *(float4*)(alef0 + (size_t)e16 * 4) =
          make_float4(r0[0] * esc_e, r0[1] * esc_e, r0[2] * esc_e, r0[3] * esc_e);
      ale1raw[e16] = r1[0];
    }
  }
}

// ---------- CSR aggregation: half-wave per edge, fully predicated rounds-of-8 ----------
template<int H, bool RELU, bool ADD_ORIG, bool INBF16, bool OUTBF16>
__global__ __launch_bounds__(256)
void agg_kernel(const int* __restrict__ rowptr, const int2* __restrict__ slotmap,
                const unsigned short* __restrict__ xs, const float* __restrict__ alef,
                const float* __restrict__ al_src, const float* __restrict__ al_dst,
                const float2* __restrict__ als1,
                const float* __restrict__ bias, const void* __restrict__ xin,
                const float* __restrict__ orig, void* __restrict__ outv, int n) {
  int wid = blockIdx.x * 4 + (threadIdx.x >> 6);
  int lane = threadIdx.x & 63;
  if (wid >= n) return;
  int half = lane >> 5;
  int l32 = lane & 31;
  int h0 = (H == 4) ? (l32 >> 3) : 0;   // lane covers channels 4*l32..4*l32+3
  const ushort4* xs4 = (const ushort4*)xs;
  float adst = al_dst[(size_t)wid * H + h0];
  float ax0 = 0.f, ax1 = 0.f, ax2 = 0.f, ax3 = 0.f, den = 0.f, sale = 0.f;
  int b = rowptr[wid], e = rowptr[wid + 1];
  int m = e - b;

#define EDGE_ACC(I_)                                                     \
  {                                                                      \
    int idx_ = (I_);                                                     \
    bool v_ = idx_ < e;                                                  \
    int ic_ = v_ ? idx_ : b;                                             \
    int s_ = slotmap[ic_].y;                                             \
    float al_, ev_;                                                      \
    if (H == 4) {                                                        \
      al_ = alef[(size_t)ic_ * 4 + h0];                                  \
      float aa_ = al_src[(size_t)s_ * 4 + h0] + adst + al_;              \
      ev_ = __expf(aa_ > 0.f ? aa_ : 0.2f * aa_);                        \
    } else {                                                             \
      float2 ae_ = als1[s_];                                             \
      al_ = alef[ic_] * ae_.y;                                           \
      float aa_ = ae_.x + adst + al_;                                    \
      ev_ = __expf(aa_ > 0.f ? aa_ : 0.2f * aa_);                        \
    }                                                                    \
    if (!v_) { ev_ = 0.f; al_ = 0.f; }                                   \
    ushort4 u_ = xs4[(size_t)s_ * 32 + l32];                             \
    ax0 = fmaf(ev_, b2f(u_.x), ax0); ax1 = fmaf(ev_, b2f(u_.y), ax1);    \
    ax2 = fmaf(ev_, b2f(u_.z), ax2); ax3 = fmaf(ev_, b2f(u_.w), ax3);    \
    den += ev_; sale += al_;                                             \
  }

  for (int k = 0; k < m; k += 8) {
    int i0 = b + k + half;
    EDGE_ACC(i0)
    EDGE_ACC(i0 + 2)
    EDGE_ACC(i0 + 4)
    EDGE_ACC(i0 + 6)
  }
#undef EDGE_ACC

  // cross-half combine (partner lane has same l32/h0)
  ax0 += __shfl_xor(ax0, 32); ax1 += __shfl_xor(ax1, 32);
  ax2 += __shfl_xor(ax2, 32); ax3 += __shfl_xor(ax3, 32);
  den += __shfl_xor(den, 32); sale += __shfl_xor(sale, 32);

  // self-loop: attr = mean of incoming alef (linear in attr)
  float la = sale / (float)(m > 1 ? m : 1);
  float asrc_w = (H == 4) ? al_src[(size_t)wid * 4 + h0] : als1[wid].x;
  float a = asrc_w + adst + la;
  float lr = a > 0.f ? a : 0.2f * a;
  float evl = __expf(lr);
  ushort4 us = xs4[(size_t)wid * 32 + l32];
  ax0 = fmaf(evl, b2f(us.x), ax0); ax1 = fmaf(evl, b2f(us.y), ax1);
  ax2 = fmaf(evl, b2f(us.z), ax2); ax3 = fmaf(evl, b2f(us.w), ax3);
  float dinv = 1.f / (den + evl + 1e-16f);
  if (half == 0) {
    float4 bi = ((const float4*)bias)[l32];
    float o0 = ax0 * dinv + bi.x;
    float o1 = ax1 * dinv + bi.y;
    float o2 = ax2 * dinv + bi.z;
    float o3 = ax3 * dinv + bi.w;
    if (INBF16) {
      ushort4 xi = ((const ushort4*)xin)[(size_t)wid * 32 + l32];
      o0 += b2f(xi.x); o1 += b2f(xi.y); o2 += b2f(xi.z); o3 += b2f(xi.w);
    } else {
      float4 xi = ((const float4*)xin)[(size_t)wid * 32 + l32];
      o0 += xi.x; o1 += xi.y; o2 += xi.z; o3 += xi.w;
    }
    if (ADD_ORIG) {
      float4 og = ((const float4*)orig)[(size_t)wid * 32 + l32];
      o0 += og.x; o1 += og.y; o2 += og.z; o3 += og.w;
    }
    if (RELU) {
      o0 = fmaxf(o0, 0.f); o1 = fmaxf(o1, 0.f);
      o2 = fmaxf(o2, 0.f); o3 = fmaxf(o3, 0.f);
    }
    if (OUTBF16) {
      ushort4 ob;
      ob.x = f2b(o0); ob.y = f2b(o1); ob.z = f2b(o2); ob.w = f2b(o3);
      ((ushort4*)outv)[(size_t)wid * 32 + l32] = ob;
    } else {
      ((float4*)outv)[(size_t)wid * 32 + l32] = make_float4(o0, o1, o2, o3);
    }
  }
}

extern "C" void kernel_launch(void* const* d_in, const int* in_sizes, int n_in,
                              void* d_out, int out_size, void* d_ws, size_t ws_size,
                              hipStream_t stream) {
  const float* x   = (const float*)d_in[0];
  const int*   ei  = (const int*)d_in[1];
  const float* ea  = (const float*)d_in[2];
  const float* ew0 = (const float*)d_in[3];
  const float* eb0 = (const float*)d_in[4];
  const float* ew1 = (const float*)d_in[5];
  const float* eb1 = (const float*)d_in[6];
  const float* ow0 = (const float*)d_in[7];
  const float* ob0 = (const float*)d_in[8];
  const float* ow1 = (const float*)d_in[9];
  const float* ob1 = (const float*)d_in[10];
  const float* g0W = (const float*)d_in[11];
  const float* g0as= (const float*)d_in[12];
  const float* g0ad= (const float*)d_in[13];
  const float* g0We= (const float*)d_in[14];
  const float* g0ae= (const float*)d_in[15];
  const float* g0b = (const float*)d_in[16];
  const float* g1W = (const float*)d_in[17];
  const float* g1as= (const float*)d_in[18];
  const float* g1ad= (const float*)d_in[19];
  const float* g1We= (const float*)d_in[20];
  const float* g1ae= (const float*)d_in[21];
  const float* g1b = (const float*)d_in[22];
  float* out = (float*)d_out;

  const int N = in_sizes[0] / D;
  const int E = in_sizes[1] / 2;
  const int* srcp = ei;
  const int* dstp = ei + E;

  char* w = (char*)d_ws;
  size_t off = 0;
  auto alloc = [&](size_t bytes) {
    void* p = w + off;
    off += (bytes + 255) & ~(size_t)255;
    return p;
  };
  size_t Nb = ((size_t)N * 4 + 255) & ~(size_t)255;
  int*   cnt     = (int*)alloc(Nb);
  int*   rank    = (int*)alloc((size_t)E * 4);
  unsigned short* xs   = (unsigned short*)alloc((size_t)N * D * 2);
  unsigned short* x1b  = (unsigned short*)alloc((size_t)N * D * 2);
  float* alef0   = (float*)alloc((size_t)E * 4 * 4);
  float* ale1raw = (float*)alloc((size_t)E * 4);
  float* al_src  = (float*)alloc((size_t)N * 4 * 4);
  float* al_dst  = (float*)alloc((size_t)N * 4 * 4);
  float* escore  = (float*)alloc((size_t)N * 4);
  float2* als1   = (float2*)alloc((size_t)N * 8);
  float* M0      = (float*)alloc(HD * 4 * 4);
  float* M1      = (float*)alloc(HD * 4);
  unsigned short* Wt0 = (unsigned short*)alloc((size_t)D * D * 2);
  unsigned short* Wt1 = (unsigned short*)alloc((size_t)D * D * 2);
  unsigned short* ewt0 = (unsigned short*)alloc((size_t)HD * ED * 2);
  unsigned short* ewt1 = (unsigned short*)alloc((size_t)HD * ED * 2);
  int*   rowptr  = (int*)alloc((size_t)(N + 1) * 4);
  int2*  slotmap = (int2*)alloc((size_t)E * 8);
  int*   bsum    = (int*)alloc(1024);
  int*   boff    = (int*)alloc(1024);

  int egrid  = (E + 255) / 256;
  int ngrid4 = (N + 3) / 4;
  int ggrid  = (N + 63) / 64;
  int nsb    = (N + 255) / 256;

  hipMemsetAsync(cnt, 0, Nb, stream);
  count_prep_kernel<<<egrid + 146, 256, 0, stream>>>(dstp, cnt, rank, E, egrid,
                                                     g0W, Wt0, g1W, Wt1,
                                                     ew0, ewt0, ew1, ewt1,
                                                     g0We, g0ae, M0, g1We, g1ae, M1);
  scan_a_kernel<<<nsb, 256, 0, stream>>>(cnt, bsum, N);
  scan_b_kernel<<<1, 256, 0, stream>>>(bsum, boff, nsb, rowptr + N, E);
  scan_c_kernel<<<nsb, 256, 0, stream>>>(cnt, boff, rowptr, N);
  fill_gemm_kernel<<<egrid + ggrid, 256, 0, stream>>>(srcp, dstp, rowptr, rank,
                                                      slotmap, E, egrid,
                                                      x, Wt0, g0as, g0ad, ow0, ob0,
                                                      xs, al_src, al_dst, escore, N);
  edge_csr_kernel<<<egrid, 256, 0, stream>>>(slotmap, ea, ewt0, ewt1,
                                             eb0, eb1, M0, M1, escore,
                                             alef0, ale1raw, E);
  // layer-0 aggregation -> x1 (bf16 in workspace)
  agg_kernel<4, true, false, false, true><<<ngrid4, 256, 0, stream>>>(
      rowptr, slotmap, xs, alef0, al_src, al_dst, nullptr,
      g0b, x, nullptr, x1b, N);
  gemm1_kernel<<<ggrid, 256, 0, stream>>>(x1b, Wt1, g1as, g1ad, ow1, ob1,
                                          xs, al_dst, als1, N);
  // layer-1 aggregation -> final f32 out (residual x1b + original x)
  agg_kernel<1, false, true, true, false><<<ngrid4, 256, 0, stream>>>(
      rowptr, slotmap, xs, ale1raw, nullptr, al_dst, als1,
      g1b, x1b, x, out, N);
}